// Round 10
// baseline (285.225 us; speedup 1.0000x reference)
//
#include <hip/hip_runtime.h>
#include <hip/hip_bf16.h>
#include <cstdint>
#include <cstddef>

typedef __bf16 bf16_t;
typedef __bf16 bf16x4 __attribute__((ext_vector_type(4)));
typedef __bf16 bf16x8 __attribute__((ext_vector_type(8)));
typedef float f32x4 __attribute__((ext_vector_type(4)));

#define GLD16(src, dst)                                                       \
    __builtin_amdgcn_global_load_lds(                                         \
        (const __attribute__((address_space(1))) void*)(src),                 \
        (__attribute__((address_space(3))) void*)(dst), 16, 0, 0)

// s_barrier WITH compiler memory fence (keep: prevents IR-level motion).
#define BAR() asm volatile("s_barrier" ::: "memory")
#define WAIT_VM4() asm volatile("s_waitcnt vmcnt(4)" ::: "memory")
#define WAIT_VM6() asm volatile("s_waitcnt vmcnt(6)" ::: "memory")
#define WAIT_VM0() asm volatile("s_waitcnt vmcnt(0)" ::: "memory")

// ---------------------------------------------------------------------------
// x fp32 -> bf16, vectorized (G13)
// ---------------------------------------------------------------------------
__global__ __launch_bounds__(256) void cvt_x_kernel(const float* __restrict__ x,
                                                    bf16_t* __restrict__ xb, int n4) {
    int idx = blockIdx.x * blockDim.x + threadIdx.x;
    int stride = gridDim.x * blockDim.x;
    const f32x4* xv = (const f32x4*)x;
    bf16x4* ov = (bf16x4*)xb;
    for (int i = idx; i < n4; i += stride) {
        f32x4 v = xv[i];
        bf16x4 o;
        o[0] = (bf16_t)v[0];
        o[1] = (bf16_t)v[1];
        o[2] = (bf16_t)v[2];
        o[3] = (bf16_t)v[3];
        ov[i] = o;
    }
}

// ---------------------------------------------------------------------------
// Build Mt[n][k] (bf16, [N][K]) from the quaternion Hamilton block structure.
// ---------------------------------------------------------------------------
__global__ __launch_bounds__(256) void pack_w_kernel(const float* __restrict__ Wa,
                                                     const float* __restrict__ Wb,
                                                     const float* __restrict__ Wc,
                                                     const float* __restrict__ Wd,
                                                     bf16_t* __restrict__ Mt) {
    __shared__ float tile[64][65];
    const int kb = blockIdx.x * 64;
    const int nb = blockIdx.y * 64;
    const int i = kb >> 10;
    const int j = nb >> 10;

    const float* W[4] = {Wa, Wb, Wc, Wd};
    const int srcIdx[4][4] = {{0, 1, 2, 3}, {1, 0, 3, 2}, {2, 3, 0, 1}, {3, 2, 1, 0}};
    const float sgn[4][4] = {{1.f, 1.f, 1.f, 1.f},
                             {-1.f, 1.f, -1.f, 1.f},
                             {-1.f, 1.f, 1.f, -1.f},
                             {-1.f, -1.f, 1.f, 1.f}};
    const float* Ws = W[srcIdx[i][j]];
    const float s = sgn[i][j];

    const int kq = kb & 1023;
    const int nq = nb & 1023;
    const int tx = threadIdx.x & 63;
    const int ty = threadIdx.x >> 6;

    for (int r = ty; r < 64; r += 4)
        tile[r][tx] = Ws[(size_t)(kq + r) * 1024 + (nq + tx)];
    __syncthreads();
    for (int r = ty; r < 64; r += 4)
        Mt[(size_t)(nb + r) * 4096 + (kb + tx)] = (bf16_t)(s * tile[tx][r]);
}

// ---------------------------------------------------------------------------
// 256x256 8-phase GEMM, C = A[M][K] * Bt[N][K]^T + bias.
// 512 threads = 8 waves (2Mx4N). BK=64, 128B per tile row.
// LDS 128 KiB: A dbuf [0,64K), B dbuf [64K,128K); half-tile = [128 rows][64 k].
// T2 swizzle: 16B-block' = block ^ (row&7); linear gload_lds dest +
// inverse-permuted global source (rule 21); read slot ((4c+l4)^(l15&7))*16.
//
// SYNC PROTOCOL (R9 lesson): global_load_lds lands asynchronously; a wave may
// read a region staged by ANOTHER wave only after (all issuers' vmcnt drain
// covering those loads) + a COMMON BARRIER.  R8/R9's p3 shadow reads ran
// after the wave's OWN VM6 but before the barrier -> cross-wave race.
// Fix: counted VM4 at p2 (drains everything except Bh0/Bh1(t+2)) + p2-end
// barrier => ALL of t+1 resident before the p3 shadow reads.  No tile-end
// vmcnt at all; t+2's loads ride through the boundary (6 outstanding).
//   p0: stageA(idle,h1,t+1) | BAR | rd amh0-m23; mmac00; rd b1        | BAR
//   p1: stageB(live,h0,t+2) | BAR | mmac01; rd amh1-m01               | BAR
//   p2: stageB(live,h1,t+2) | BAR | rd amh1-m23; mmac11; VM4(/VM0)    | BAR
//   p3: stageA(live,h0,t+2) | BAR | mmac10; rd b0',amh0'-m01 (t+1)    | BAR
// Stage-side (WAR) ledger: every staged region's t-data reads are consumed
// (compiler lgkm before the consuming mmac) >=1 common barrier before the
// stage issue; mmac10 reuses amh1 REGISTERS only (LDS reads done by p2-end).
// ---------------------------------------------------------------------------
__global__ __launch_bounds__(512, 2) void qgemm_kernel(const bf16_t* __restrict__ A,
                                                       const bf16_t* __restrict__ Bt,
                                                       const float* __restrict__ bias,
                                                       float* __restrict__ C) {
    constexpr int N = 4096, K = 4096;
    constexpr int NT = K / 64;
    extern __shared__ __align__(16) char lds[];

    const int tid = threadIdx.x;
    const int w = tid >> 6;
    const int lane = tid & 63;
    const int l15 = lane & 15, l4 = lane >> 4;
    const int wr = w >> 2, wc = w & 3;  // 2 x 4 wave grid

    // XCD-aware swizzle (512 = 8*64, bijective)
    const int wg = blockIdx.x;
    const int swz = (wg & 7) * 64 + (wg >> 3);
    const int brow = (swz >> 4) * 256;  // 32 tile rows
    const int bcol = (swz & 15) * 256;  // 16 tile cols

    // staging: LDS stores k-block' = kb ^ (row&7); dest linear, global source
    // k-block for lane slot (lane&7) at row (lane>>3) is the inverse perm:
    const int srow = lane >> 3;
    const int skb = (lane & 7) ^ (lane >> 3);

    auto stageA = [&](int buf, int h, int tt) {
#pragma unroll
        for (int q = 0; q < 2; ++q) {
            const bf16_t* src = A + (size_t)(brow + h * 128 + w * 16 + q * 8 + srow) * K +
                                tt * 64 + skb * 8;
            GLD16(src, lds + buf * 32768 + h * 16384 + w * 2048 + q * 1024);
        }
    };
    auto stageB = [&](int buf, int h, int tt) {
#pragma unroll
        for (int q = 0; q < 2; ++q) {
            const bf16_t* src = Bt + (size_t)(bcol + h * 128 + w * 16 + q * 8 + srow) * K +
                                tt * 64 + skb * 8;
            GLD16(src, lds + 65536 + buf * 32768 + h * 16384 + w * 2048 + q * 1024);
        }
    };

    f32x4 acc[8][4] = {};
    bf16x8 a[4][2], b0[2][2], b1[2][2];

    // one A m-frag (2 reads): row = wr-half, mh sub-half, frag m
    auto ldAm = [&](int buf, int mh, int m) {
#pragma unroll
        for (int c = 0; c < 2; ++c)
            a[m][c] = *(const bf16x8*)(lds + buf * 32768 + wr * 16384 +
                                       (mh * 64 + m * 16 + l15) * 128 +
                                       ((c * 4 + l4) ^ (l15 & 7)) * 16);
    };
    // B frags: nh selects the STAGING half; wave cols = nh*128 + wc*32 + n*16
    auto ldB = [&](int buf, int nh, bf16x8(&b)[2][2]) {
#pragma unroll
        for (int n = 0; n < 2; ++n)
#pragma unroll
            for (int c = 0; c < 2; ++c)
                b[n][c] = *(const bf16x8*)(lds + 65536 + buf * 32768 + nh * 16384 +
                                           (wc * 32 + n * 16 + l15) * 128 +
                                           ((c * 4 + l4) ^ (l15 & 7)) * 16);
    };
    auto mmac = [&](int mh, int nh, bf16x8(&b)[2][2]) {
        __builtin_amdgcn_s_setprio(1);
#pragma unroll
        for (int m = 0; m < 4; ++m)
#pragma unroll
            for (int n = 0; n < 2; ++n)
#pragma unroll
                for (int c = 0; c < 2; ++c)
                    acc[mh * 4 + m][nh * 2 + n] = __builtin_amdgcn_mfma_f32_16x16x32_bf16(
                        a[m][c], b[n][c], acc[mh * 4 + m][nh * 2 + n], 0, 0, 0);
        __builtin_amdgcn_s_setprio(0);
    };

    // prologue: tile0 full (8 loads, buf0) + tile1's Bh0/Bh1/Ah0 (6 loads, buf1);
    // VM6 drains tile0 (issuer drain), BAR = common barrier, THEN preload reads.
    stageA(0, 0, 0);
    stageA(0, 1, 0);
    stageB(0, 0, 0);
    stageB(0, 1, 0);
    stageB(1, 0, 1);
    stageB(1, 1, 1);
    stageA(1, 0, 1);
    WAIT_VM6();
    BAR();
    ldB(0, 0, b0);
    ldAm(0, 0, 0);
    ldAm(0, 0, 1);

    for (int tt = 0; tt < NT; ++tt) {
        const int cur = tt & 1;
        // phase 0: (mh0,nh0); stage A h1 of t+1 (idle buf)
        if (tt + 1 < NT) stageA(cur ^ 1, 1, tt + 1);
        BAR();
        ldAm(cur, 0, 2);
        ldAm(cur, 0, 3);
        mmac(0, 0, b0);
        ldB(cur, 1, b1);  // Bh1(t): reads run under mmac00's pipe drain
        BAR();
        // phase 1: (mh0,nh1); stage B h0 of t+2 (live buf)
        if (tt + 2 < NT) stageB(cur, 0, tt + 2);
        BAR();
        mmac(0, 1, b1);
        ldAm(cur, 1, 0);  // amh1 m0,m1
        ldAm(cur, 1, 1);
        BAR();
        // phase 2: (mh1,nh1); stage B h1 of t+2 (live buf); counted drain
        if (tt + 2 < NT) stageB(cur, 1, tt + 2);
        BAR();
        ldAm(cur, 1, 2);
        ldAm(cur, 1, 3);
        mmac(1, 1, b1);
        // VM4: FIFO-drains everything except Bh0/Bh1(t+2) -> ALL of t+1
        // (incl. Ah1(t+1)@p0) landed; p2-end BAR makes it common knowledge.
        if (tt + 2 < NT) {
            WAIT_VM4();
        } else {
            WAIT_VM0();  // tail: no t+2 loads in flight; drain t+1 fully
        }
        BAR();
        // phase 3: (mh1,nh0); stage A h0 of t+2 (live buf)
        if (tt + 2 < NT) stageA(cur, 0, tt + 2);
        BAR();
        mmac(1, 0, b0);
        if (tt + 1 < NT) {
            ldB(cur ^ 1, 0, b0);  // b0(t+1): safe (drained at p2 + barrier)
            ldAm(cur ^ 1, 0, 0);  // amh0(t+1) m0,m1
            ldAm(cur ^ 1, 0, 1);
        }
        BAR();
    }

    // epilogue: C/D layout col = lane&15, row = (lane>>4)*4 + i.
    // B mapping: global n -> col = (n>>1)*128 + wc*32 + (n&1)*16
#pragma unroll
    for (int n = 0; n < 4; ++n) {
        const int col = bcol + (n >> 1) * 128 + wc * 32 + (n & 1) * 16 + l15;
        const float bv = bias[col];
#pragma unroll
        for (int m = 0; m < 8; ++m) {
            const int row0 = brow + wr * 128 + m * 16 + l4 * 4;
            const f32x4 v = acc[m][n];
#pragma unroll
            for (int i = 0; i < 4; ++i)
                C[(size_t)(row0 + i) * N + col] = v[i] + bv;
        }
    }
}

// ---------------------------------------------------------------------------
extern "C" void kernel_launch(void* const* d_in, const int* in_sizes, int n_in,
                              void* d_out, int out_size, void* d_ws, size_t ws_size,
                              hipStream_t stream) {
    const float* x = (const float*)d_in[0];
    const float* Wa = (const float*)d_in[1];
    const float* Wb = (const float*)d_in[2];
    const float* Wc = (const float*)d_in[3];
    const float* Wd = (const float*)d_in[4];
    const float* bias = (const float*)d_in[5];
    float* out = (float*)d_out;

    const int M = 8192, N = 4096, K = 4096;

    bf16_t* xb = (bf16_t*)d_ws;       // [M][K] bf16
    bf16_t* Mt = xb + (size_t)M * K;  // [N][K] bf16

    cvt_x_kernel<<<4096, 256, 0, stream>>>(x, xb, (M * K) / 4);
    pack_w_kernel<<<dim3(64, 64), 256, 0, stream>>>(Wa, Wb, Wc, Wd, Mt);

    (void)hipFuncSetAttribute((const void*)qgemm_kernel,
                              hipFuncAttributeMaxDynamicSharedMemorySize, 131072);
    qgemm_kernel<<<dim3((M / 256) * (N / 256)), 512, 131072, stream>>>(xb, Mt, bias, out);
}